// Round 2
// baseline (708.607 us; speedup 1.0000x reference)
//
#include <hip/hip_runtime.h>
#include <math.h>

#define B_ 128
#define C_ 273
#define T_ 2048
#define O_ 270
#define D_ 288   // fourier dim; also the K of k_scores
#define OP_ 288  // O padded
#define CP_ 384  // C padded (emb rows, N of k_scores)
#define KP_ 288  // K stride for wbf / megT

typedef __attribute__((ext_vector_type(8))) short short8;  // 8 x bf16 (4 VGPR)
typedef __attribute__((ext_vector_type(4))) float f32x4;   // MFMA acc

__device__ inline ushort f2bf(float f) {  // RNE fp32 -> bf16
    uint u = __float_as_uint(f);
    return (ushort)((u + 0x7FFFu + ((u >> 16) & 1u)) >> 16);
}
__device__ inline uint pack2bf(float lo, float hi) {
    return (uint)f2bf(lo) | ((uint)f2bf(hi) << 16);
}

// ---------------------------------------------------------------------------
// K1: Fourier embedding -> bf16, padded rows [B][CP_][288], rows c>=273 zero.
// __sincosf: native v_sin/v_cos (args <= ~138 rad; err ~1e-5 << bf16 ulp).
// ---------------------------------------------------------------------------
__global__ __launch_bounds__(256) void k_emb(const float* __restrict__ pos,
                                             ushort* __restrict__ emb) {
    int idx = blockIdx.x * 256 + threadIdx.x;
    const int total = B_ * CP_ * 144;
    if (idx >= total) return;
    int bc = idx / 144;
    int k  = idx - bc * 144;
    int b  = bc / CP_;
    int c  = bc - b * CP_;
    ushort* row = emb + ((size_t)b * CP_ + c) * D_;
    if (c >= C_) { row[k] = 0; row[144 + k] = 0; return; }
    int i = k / 12, j = k - i * 12;
    float px = pos[((size_t)b * C_ + c) * 2 + 0] + 0.2f;
    float py = pos[((size_t)b * C_ + c) * 2 + 1] + 0.2f;
    const float w0 = 4.48798950512827605f; // 2*pi/1.4
    float loc = px * (w0 * (float)i) + py * (w0 * (float)j);
    float s, cc;
    __sincosf(loc, &s, &cc);
    row[k]       = f2bf(cc);
    row[144 + k] = f2bf(s);
}

// ---------------------------------------------------------------------------
// K2: gather per-subject heads -> bf16 [B][OP_][288], rows o>=270 zero.
// ---------------------------------------------------------------------------
__global__ __launch_bounds__(256) void k_gather(const float* __restrict__ heads,
                                                const int* __restrict__ sids,
                                                ushort* __restrict__ hb) {
    int idx = blockIdx.x * 256 + threadIdx.x;
    const int total = B_ * OP_ * (D_ / 8);
    if (idx >= total) return;
    int d8 = (idx % 36) * 8;
    int t  = idx / 36;
    int o  = t % OP_;
    int b  = t / OP_;
    uint4 outv = make_uint4(0, 0, 0, 0);
    if (o < O_) {
        int sid = sids[b];
        const float* src = heads + ((size_t)sid * O_ + o) * D_ + d8;
        float4 v0 = *(const float4*)src;
        float4 v1 = *(const float4*)(src + 4);
        outv.x = pack2bf(v0.x, v0.y); outv.y = pack2bf(v0.z, v0.w);
        outv.z = pack2bf(v1.x, v1.y); outv.w = pack2bf(v1.z, v1.w);
    }
    *(uint4*)(hb + ((size_t)b * OP_ + o) * D_ + d8) = outv;
}

// ---------------------------------------------------------------------------
// Shared GEMM staging: per K-step, A tile 96x32 bf16 (384 16B slots) and
// B tile 128x32 bf16 (512 slots) via global_load_lds width=16.
// LDS buffer layout (uints): [A: 0..1535][B: 1536..3583]; double-buffered.
// Both operands have row stride KP_=288 ushorts (16B-aligned rows).
// dst base is wave-uniform; HW writes base + lane*16 (linear LDS required).
// Slot mapping (row = slot>>2, kchunk = slot&3) byte-identical to the
// round-0 verified manual staging layout.
// ---------------------------------------------------------------------------
__device__ inline void stage_ab(const ushort* __restrict__ A0,
                                const ushort* __restrict__ B0,
                                uint* buf, int wid, int lane) {
    for (int ch = wid; ch < 14; ch += 4) {
        bool isA = ch < 6;
        int slotb = (isA ? ch : ch - 6) << 6;      // chunk base slot
        int slot  = slotb + lane;                  // per-lane 16B slot
        const ushort* g = (isA ? A0 : B0) + (size_t)(slot >> 2) * KP_ + ((slot & 3) << 3);
        uint* dst = buf + (isA ? (slotb << 2) : (1536 + (slotb << 2)));
        __builtin_amdgcn_global_load_lds(
            (const __attribute__((address_space(1))) uint*)g,
            (__attribute__((address_space(3))) uint*)dst, 16, 0, 0);
    }
}

// ---------------------------------------------------------------------------
// K3: scores = hb @ emb^T  (bf16 MFMA, M=270->288, N=273->384, K=288)
// Block: 96(M) x 128(N), 4 waves (2x2), wave = 48x64 = 3x4 MFMA 16x16x32.
// 2-phase double-buffered global_load_lds pipeline (T3-lite).
// ---------------------------------------------------------------------------
__global__ __launch_bounds__(256) void k_scores(const ushort* __restrict__ hb,
                                                const ushort* __restrict__ emb,
                                                float* __restrict__ scores) {
    __shared__ uint LdsU[2 * 3584];  // 28.7 KB
    int b  = blockIdx.z;
    int o0 = blockIdx.y * 96;
    int n0 = blockIdx.x * 128;
    int tid = threadIdx.x;
    int wid = tid >> 6, lane = tid & 63;
    int wm = wid >> 1, wn = wid & 1;
    int lm = lane & 15, lq = lane >> 4;
    const ushort* Ab = hb  + ((size_t)b * OP_ + o0) * D_;
    const ushort* Bb = emb + ((size_t)b * CP_ + n0) * D_;
    f32x4 acc[3][4];
    #pragma unroll
    for (int i = 0; i < 3; ++i)
        #pragma unroll
        for (int j = 0; j < 4; ++j) { f32x4 z = {0.f, 0.f, 0.f, 0.f}; acc[i][j] = z; }

    auto compute = [&](int cb) {
        const ushort* As = (const ushort*)(LdsU + cb * 3584);
        const ushort* Bs = (const ushort*)(LdsU + cb * 3584 + 1536);
        short8 a[3], bv[4];
        #pragma unroll
        for (int fm = 0; fm < 3; ++fm)
            a[fm] = *(const short8*)(As + (wm * 48 + fm * 16 + lm) * 32 + lq * 8);
        #pragma unroll
        for (int fn = 0; fn < 4; ++fn)
            bv[fn] = *(const short8*)(Bs + (wn * 64 + fn * 16 + lm) * 32 + lq * 8);
        #pragma unroll
        for (int fm = 0; fm < 3; ++fm)
            #pragma unroll
            for (int fn = 0; fn < 4; ++fn)
                acc[fm][fn] = __builtin_amdgcn_mfma_f32_16x16x32_bf16(a[fm], bv[fn], acc[fm][fn], 0, 0, 0);
    };

    int cur = 0;
    stage_ab(Ab, Bb, LdsU, wid, lane);      // k0 = 0
    __syncthreads();                         // vmcnt(0) + barrier
    for (int k = 0; k < 8; ++k) {
        int nk = (k + 1) * 32;
        stage_ab(Ab + nk, Bb + nk, LdsU + (cur ^ 1) * 3584, wid, lane);  // prefetch
        compute(cur);                        // overlap with in-flight loads
        __syncthreads();                     // drains prefetch; protects reuse
        cur ^= 1;
    }
    compute(cur);                            // k0 = 256 (no prefetch)

    // D layout: row(m) = lq*4 + reg, col(n) = lm   [verified m89/m91]
    #pragma unroll
    for (int fm = 0; fm < 3; ++fm) {
        int obase = o0 + wm * 48 + fm * 16 + lq * 4;
        #pragma unroll
        for (int fn = 0; fn < 4; ++fn) {
            int c = n0 + wn * 64 + fn * 16 + lm;
            if (c >= C_) continue;
            #pragma unroll
            for (int r = 0; r < 4; ++r) {
                int o = obase + r;
                if (o < O_) scores[((size_t)b * O_ + o) * C_ + c] = acc[fm][fn][r];
            }
        }
    }
}

// ---------------------------------------------------------------------------
// K4: softmax over c; writes bf16 weights [B][OP_][KP_], pads zeroed.
// ---------------------------------------------------------------------------
__global__ __launch_bounds__(256) void k_softmax(const float* __restrict__ scores,
                                                 const float* __restrict__ pos,
                                                 ushort* __restrict__ wbf) {
    int wave = threadIdx.x >> 6, lane = threadIdx.x & 63;
    int row = blockIdx.x * 4 + wave;   // over B_*OP_
    if (row >= B_ * OP_) return;
    int b = row / OP_, o = row - b * OP_;
    ushort* wrow = wbf + ((size_t)b * OP_ + o) * KP_;
    if (o >= O_) {
        #pragma unroll
        for (int ch = 0; ch < 5; ++ch) { int c = lane + ch * 64; if (c < KP_) wrow[c] = 0; }
        return;
    }
    const float* srow = scores + ((size_t)b * O_ + o) * C_;
    const float* prow = pos + (size_t)b * C_ * 2;
    float v[5];
    float m = -INFINITY;
    #pragma unroll
    for (int ch = 0; ch < 5; ++ch) {
        int c = lane + ch * 64;
        float s = -INFINITY;
        if (c < C_) {
            s = srow[c];
            float px = prow[c * 2], py = prow[c * 2 + 1];
            if (px == -0.1f && py == -0.1f) s = -INFINITY;
        }
        v[ch] = s;
        m = fmaxf(m, s);
    }
    #pragma unroll
    for (int off = 32; off; off >>= 1) m = fmaxf(m, __shfl_xor(m, off, 64));
    float sum = 0.f;
    #pragma unroll
    for (int ch = 0; ch < 5; ++ch) {
        v[ch] = __expf(v[ch] - m);
        if (lane + ch * 64 < C_) sum += v[ch];
    }
    #pragma unroll
    for (int off = 32; off; off >>= 1) sum += __shfl_xor(sum, off, 64);
    float inv = 1.0f / sum;
    #pragma unroll
    for (int ch = 0; ch < 5; ++ch) {
        int c = lane + ch * 64;
        if (c < C_) wrow[c] = f2bf(v[ch] * inv);
        else if (c < KP_) wrow[c] = 0;
    }
}

// ---------------------------------------------------------------------------
// K4.5: megT = bf16 transpose of meg: [B][T_][KP_], c>=273 zeroed.
// LDS-tiled (64c x 64t), stride-65 fp32 tile => conflict-free scalar ds ops.
// Pure streaming: read 286 MB fp32 coalesced, write 151 MB bf16 coalesced.
// ---------------------------------------------------------------------------
__global__ __launch_bounds__(256) void k_megT(const float* __restrict__ meg,
                                              ushort* __restrict__ megT) {
    __shared__ float lds[64 * 65];
    int b  = blockIdx.z;
    int t0 = blockIdx.x * 64;
    int c0 = blockIdx.y * 64;
    int tid = threadIdx.x;
    const float* Mb = meg + (size_t)b * C_ * T_;
    #pragma unroll
    for (int i = 0; i < 4; ++i) {
        int slot = tid + i * 256;          // 1024 slots = 64 rows x 16 float4
        int r = slot >> 4, q = slot & 15;
        float4 v = make_float4(0.f, 0.f, 0.f, 0.f);
        if (c0 + r < C_) v = *(const float4*)(Mb + (size_t)(c0 + r) * T_ + t0 + q * 4);
        lds[r * 65 + q * 4 + 0] = v.x;
        lds[r * 65 + q * 4 + 1] = v.y;
        lds[r * 65 + q * 4 + 2] = v.z;
        lds[r * 65 + q * 4 + 3] = v.w;
    }
    __syncthreads();
    ushort* Tb = megT + (size_t)b * T_ * KP_;
    #pragma unroll
    for (int i = 0; i < 2; ++i) {
        int slot = tid + i * 256;          // 512 slots = 64 t-rows x 8 uint4
        int t = slot >> 3, co = (slot & 7) * 8;
        int c = c0 + co;
        if (c >= KP_) continue;            // c-tile 256..319: write only c<288
        uint4 w;
        w.x = pack2bf(lds[(co + 0) * 65 + t], lds[(co + 1) * 65 + t]);
        w.y = pack2bf(lds[(co + 2) * 65 + t], lds[(co + 3) * 65 + t]);
        w.z = pack2bf(lds[(co + 4) * 65 + t], lds[(co + 5) * 65 + t]);
        w.w = pack2bf(lds[(co + 6) * 65 + t], lds[(co + 7) * 65 + t]);
        *(uint4*)(Tb + (size_t)(t0 + t) * KP_ + c) = w;
    }
}

// ---------------------------------------------------------------------------
// K5 (new): out = wbf @ megT. Both operands bf16 K-contig.
// Same 2-phase global_load_lds pipeline as k_scores. M=270->288, N=2048, K=288.
// ---------------------------------------------------------------------------
__global__ __launch_bounds__(256) void k_out(const ushort* __restrict__ megT,
                                             const ushort* __restrict__ wbf,
                                             float* __restrict__ out) {
    __shared__ uint LdsU[2 * 3584];
    int b  = blockIdx.z;
    int o0 = blockIdx.y * 96;
    int t0 = blockIdx.x * 128;
    int tid = threadIdx.x;
    int wid = tid >> 6, lane = tid & 63;
    int wm = wid >> 1, wn = wid & 1;
    int lm = lane & 15, lq = lane >> 4;
    const ushort* Ab = wbf  + ((size_t)b * OP_ + o0) * KP_;
    const ushort* Bb = megT + ((size_t)b * T_ + t0) * KP_;
    f32x4 acc[3][4];
    #pragma unroll
    for (int i = 0; i < 3; ++i)
        #pragma unroll
        for (int j = 0; j < 4; ++j) { f32x4 z = {0.f, 0.f, 0.f, 0.f}; acc[i][j] = z; }

    auto compute = [&](int cb) {
        const ushort* As = (const ushort*)(LdsU + cb * 3584);
        const ushort* Bs = (const ushort*)(LdsU + cb * 3584 + 1536);
        short8 a[3], bv[4];
        #pragma unroll
        for (int fm = 0; fm < 3; ++fm)
            a[fm] = *(const short8*)(As + (wm * 48 + fm * 16 + lm) * 32 + lq * 8);
        #pragma unroll
        for (int fn = 0; fn < 4; ++fn)
            bv[fn] = *(const short8*)(Bs + (wn * 64 + fn * 16 + lm) * 32 + lq * 8);
        #pragma unroll
        for (int fm = 0; fm < 3; ++fm)
            #pragma unroll
            for (int fn = 0; fn < 4; ++fn)
                acc[fm][fn] = __builtin_amdgcn_mfma_f32_16x16x32_bf16(a[fm], bv[fn], acc[fm][fn], 0, 0, 0);
    };

    int cur = 0;
    stage_ab(Ab, Bb, LdsU, wid, lane);
    __syncthreads();
    for (int k = 0; k < 8; ++k) {
        int nk = (k + 1) * 32;
        stage_ab(Ab + nk, Bb + nk, LdsU + (cur ^ 1) * 3584, wid, lane);
        compute(cur);
        __syncthreads();
        cur ^= 1;
    }
    compute(cur);

    #pragma unroll
    for (int fm = 0; fm < 3; ++fm) {
        int obase = o0 + wm * 48 + fm * 16 + lq * 4;
        #pragma unroll
        for (int fn = 0; fn < 4; ++fn) {
            int t = t0 + wn * 64 + fn * 16 + lm;
            #pragma unroll
            for (int r = 0; r < 4; ++r) {
                int o = obase + r;
                if (o < O_) out[((size_t)b * O_ + o) * T_ + t] = acc[fm][fn][r];
            }
        }
    }
}

// ---------------------------------------------------------------------------
// K5 fallback (round-0 fused-transpose version) if workspace can't hold megT.
// ---------------------------------------------------------------------------
__global__ __launch_bounds__(256) void k_out_fused(const float* __restrict__ meg,
                                                   const ushort* __restrict__ wbf,
                                                   float* __restrict__ out) {
    __shared__ uint AsU[96 * 16];
    __shared__ uint BsU[128 * 16];
    int b  = blockIdx.z;
    int o0 = blockIdx.y * 96;
    int t0 = blockIdx.x * 128;
    int tid = threadIdx.x;
    int wid = tid >> 6, lane = tid & 63;
    int wm = wid >> 1, wn = wid & 1;
    int lm = lane & 15, lq = lane >> 4;
    const ushort* Ab = wbf + (size_t)b * OP_ * KP_;
    const float*  Mb = meg + (size_t)b * C_ * T_;
    f32x4 acc[3][4];
    #pragma unroll
    for (int i = 0; i < 3; ++i)
        #pragma unroll
        for (int j = 0; j < 4; ++j) { f32x4 z = {0.f, 0.f, 0.f, 0.f}; acc[i][j] = z; }

    int cpair = tid & 15;
    int tq0   = tid >> 4;

    for (int k0 = 0; k0 < KP_; k0 += 32) {
        {
            int row = tid >> 2, ch = tid & 3;
            uint4 v = *(const uint4*)(Ab + (size_t)(o0 + row) * KP_ + k0 + ch * 8);
            *(uint4*)&AsU[tid * 4] = v;
            if (tid < 128) {
                int s2 = 256 + tid, row2 = s2 >> 2, ch2 = s2 & 3;
                uint4 v2 = *(const uint4*)(Ab + (size_t)(o0 + row2) * KP_ + k0 + ch2 * 8);
                *(uint4*)&AsU[s2 * 4] = v2;
            }
        }
        #pragma unroll
        for (int it = 0; it < 2; ++it) {
            int tqq = tq0 + it * 16;
            int c   = k0 + cpair * 2;
            int t   = tqq * 4;
            float4 v0 = make_float4(0.f, 0.f, 0.f, 0.f);
            float4 v1 = make_float4(0.f, 0.f, 0.f, 0.f);
            if (c < C_)     v0 = *(const float4*)(Mb + (size_t)c * T_ + t0 + t);
            if (c + 1 < C_) v1 = *(const float4*)(Mb + (size_t)(c + 1) * T_ + t0 + t);
            BsU[(t + 0) * 16 + cpair] = pack2bf(v0.x, v1.x);
            BsU[(t + 1) * 16 + cpair] = pack2bf(v0.y, v1.y);
            BsU[(t + 2) * 16 + cpair] = pack2bf(v0.z, v1.z);
            BsU[(t + 3) * 16 + cpair] = pack2bf(v0.w, v1.w);
        }
        __syncthreads();
        short8 a[3], bb[4];
        #pragma unroll
        for (int fm = 0; fm < 3; ++fm)
            a[fm] = *(short8*)((ushort*)AsU + (wm * 48 + fm * 16 + lm) * 32 + lq * 8);
        #pragma unroll
        for (int fn = 0; fn < 4; ++fn)
            bb[fn] = *(short8*)((ushort*)BsU + (wn * 64 + fn * 16 + lm) * 32 + lq * 8);
        #pragma unroll
        for (int fm = 0; fm < 3; ++fm)
            #pragma unroll
            for (int fn = 0; fn < 4; ++fn)
                acc[fm][fn] = __builtin_amdgcn_mfma_f32_16x16x32_bf16(a[fm], bb[fn], acc[fm][fn], 0, 0, 0);
        __syncthreads();
    }
    #pragma unroll
    for (int fm = 0; fm < 3; ++fm) {
        int obase = o0 + wm * 48 + fm * 16 + lq * 4;
        #pragma unroll
        for (int fn = 0; fn < 4; ++fn) {
            int t = t0 + wn * 64 + fn * 16 + lm;
            #pragma unroll
            for (int r = 0; r < 4; ++r) {
                int o = obase + r;
                if (o < O_) out[((size_t)b * O_ + o) * T_ + t] = acc[fm][fn][r];
            }
        }
    }
}

// ---------------------------------------------------------------------------
extern "C" void kernel_launch(void* const* d_in, const int* in_sizes, int n_in,
                              void* d_out, int out_size, void* d_ws, size_t ws_size,
                              hipStream_t stream) {
    const float* meg   = (const float*)d_in[0];
    const float* pos   = (const float*)d_in[1];
    const int*   sids  = (const int*)d_in[2];
    const float* heads = (const float*)d_in[3];
    float* out = (float*)d_out;

    // ws layout (bytes):
    //   emb/wbf @ 0          : 28,311,552   (wbf aliases emb; emb dead after k_scores)
    //   hb      @ 28,311,552 : 21,233,664   (dead after k_scores)
    //   scores  @ 49,545,216 : 37,739,520   (dead after k_softmax)
    //   megT    @ 28,311,552 : 150,994,944  (aliases hb+scores; live k_megT -> k_out)
    // total needed for new path: 179,306,496 B
    const size_t embElems = (size_t)B_ * CP_ * D_;        // ushorts
    const size_t hbElems  = (size_t)B_ * OP_ * D_;
    ushort* emb = (ushort*)d_ws;
    ushort* wbf = emb;
    ushort* hb  = emb + embElems;
    float* scores = (float*)(hb + hbElems);
    ushort* megT  = hb;  // aliases hb+scores after they die
    const size_t need_new = embElems * 2 + (size_t)B_ * T_ * KP_ * 2;

    k_emb<<<(B_ * CP_ * 144 + 255) / 256, 256, 0, stream>>>(pos, emb);
    k_gather<<<(B_ * OP_ * 36 + 255) / 256, 256, 0, stream>>>(heads, sids, hb);
    k_scores<<<dim3(3, 3, B_), 256, 0, stream>>>(hb, emb, scores);
    k_softmax<<<(B_ * OP_ + 3) / 4, 256, 0, stream>>>(scores, pos, wbf);
    if (ws_size >= need_new) {
        k_megT<<<dim3(T_ / 64, 5, B_), 256, 0, stream>>>(meg, megT);
        k_out<<<dim3(T_ / 128, 3, B_), 256, 0, stream>>>(megT, wbf, out);
    } else {
        k_out_fused<<<dim3(T_ / 128, 3, B_), 256, 0, stream>>>(meg, wbf, out);
    }
}

// Round 3
// 698.658 us; speedup vs baseline: 1.0142x; 1.0142x over previous
//
#include <hip/hip_runtime.h>
#include <math.h>

#define B_ 128
#define C_ 273
#define T_ 2048
#define O_ 270
#define D_ 288   // fourier dim; K of the scores GEMM
#define OP_ 288  // O padded
#define CP_ 288  // C padded (emb rows; N of fused scores GEMM)
#define KP_ 288  // K stride for wbf / megT

typedef __attribute__((ext_vector_type(8))) short short8;  // 8 x bf16 (4 VGPR)
typedef __attribute__((ext_vector_type(4))) float f32x4;   // MFMA acc

__device__ inline ushort f2bf(float f) {  // RNE fp32 -> bf16
    uint u = __float_as_uint(f);
    return (ushort)((u + 0x7FFFu + ((u >> 16) & 1u)) >> 16);
}
__device__ inline uint pack2bf(float lo, float hi) {
    return (uint)f2bf(lo) | ((uint)f2bf(hi) << 16);
}

// m204 bijective XCD swizzle: consecutive decoded ids share an XCD.
__device__ inline int xcd_swz(int h, int nwg) {
    int q = nwg >> 3, r = nwg & 7, x = h & 7, s = h >> 3;
    return (x < r ? x * (q + 1) : r * (q + 1) + (x - r) * q) + s;
}

// ---------------------------------------------------------------------------
// K1: Fourier embedding -> bf16, padded rows [B][CP_][288], rows c>=273 zero.
// ---------------------------------------------------------------------------
__global__ __launch_bounds__(256) void k_emb(const float* __restrict__ pos,
                                             ushort* __restrict__ emb) {
    int idx = blockIdx.x * 256 + threadIdx.x;
    const int total = B_ * CP_ * 144;
    if (idx >= total) return;
    int bc = idx / 144;
    int k  = idx - bc * 144;
    int b  = bc / CP_;
    int c  = bc - b * CP_;
    ushort* row = emb + ((size_t)b * CP_ + c) * D_;
    if (c >= C_) { row[k] = 0; row[144 + k] = 0; return; }
    int i = k / 12, j = k - i * 12;
    float px = pos[((size_t)b * C_ + c) * 2 + 0] + 0.2f;
    float py = pos[((size_t)b * C_ + c) * 2 + 1] + 0.2f;
    const float w0 = 4.48798950512827605f; // 2*pi/1.4
    float loc = px * (w0 * (float)i) + py * (w0 * (float)j);
    float s, cc;
    __sincosf(loc, &s, &cc);
    row[k]       = f2bf(cc);
    row[144 + k] = f2bf(s);
}

// ---------------------------------------------------------------------------
// K2: gather per-subject heads -> bf16 [B][OP_][288], rows o>=270 zero.
// ---------------------------------------------------------------------------
__global__ __launch_bounds__(256) void k_gather(const float* __restrict__ heads,
                                                const int* __restrict__ sids,
                                                ushort* __restrict__ hb) {
    int idx = blockIdx.x * 256 + threadIdx.x;
    const int total = B_ * OP_ * (D_ / 8);
    if (idx >= total) return;
    int d8 = (idx % 36) * 8;
    int t  = idx / 36;
    int o  = t % OP_;
    int b  = t / OP_;
    uint4 outv = make_uint4(0, 0, 0, 0);
    if (o < O_) {
        int sid = sids[b];
        const float* src = heads + ((size_t)sid * O_ + o) * D_ + d8;
        float4 v0 = *(const float4*)src;
        float4 v1 = *(const float4*)(src + 4);
        outv.x = pack2bf(v0.x, v0.y); outv.y = pack2bf(v0.z, v0.w);
        outv.z = pack2bf(v1.x, v1.y); outv.w = pack2bf(v1.z, v1.w);
    }
    *(uint4*)(hb + ((size_t)b * OP_ + o) * D_ + d8) = outv;
}

// ---------------------------------------------------------------------------
// Staging: ACH A-chunks then BCH B-chunks, 64 lanes x 16B per chunk, via
// global_load_lds width=16. Rows are KP_ ushorts (64B of bf16 per 32-k slice,
// 4 slots/row). dst = wave-uniform chunk base + lane*16B (linear LDS).
// ---------------------------------------------------------------------------
template<int ACH, int BCH, int BBASE>
__device__ inline void stage2(const ushort* __restrict__ A0,
                              const ushort* __restrict__ B0,
                              uint* buf, int wid, int lane) {
    for (int ch = wid; ch < ACH + BCH; ch += 4) {
        bool isA = ch < ACH;
        int cb = isA ? ch : ch - ACH;
        int slot = (cb << 6) + lane;
        const ushort* g = (isA ? A0 : B0) + (size_t)(slot >> 2) * KP_ + ((slot & 3) << 3);
        uint* dst = buf + (isA ? 0 : BBASE) + (slot << 2);
        __builtin_amdgcn_global_load_lds(
            (const __attribute__((address_space(1))) uint*)g,
            (__attribute__((address_space(3))) uint*)dst, 16, 0, 0);
    }
}

// ---------------------------------------------------------------------------
// K3 (fused): scores GEMM (M=96 o-rows, N=288 full c, K=288) + row softmax
// + bf16 weight write. Waves 2(M)x2(N), wave-tile 48x144 = 3fm x 9fn.
// Removes the fp32 scores buffer and the separate softmax kernel.
// ---------------------------------------------------------------------------
__global__ __launch_bounds__(256) void k_fused(const ushort* __restrict__ hb,
                                               const ushort* __restrict__ emb,
                                               const float* __restrict__ pos,
                                               ushort* __restrict__ wbf) {
    __shared__ uint LdsU[2 * 6144];      // per buf: A 96x32 (1536u) + B 288x32 (4608u)
    __shared__ float red[2][2][96];      // [phase][wn][row]
    int d  = xcd_swz(blockIdx.x, 3 * B_);
    int ob = d % 3, b = d / 3;
    int o0 = ob * 96;
    int tid = threadIdx.x;
    int wid = tid >> 6, lane = tid & 63;
    int wm = wid >> 1, wn = wid & 1;
    int lm = lane & 15, lq = lane >> 4;
    const ushort* Ab = hb  + ((size_t)b * OP_ + o0) * D_;
    const ushort* Bb = emb + (size_t)b * CP_ * D_;

    // per-lane column bias: 0 valid, -inf for invalid pos or c>=273
    const float* prow = pos + (size_t)b * C_ * 2;
    float bias[9];
    #pragma unroll
    for (int fn = 0; fn < 9; ++fn) {
        int c = wn * 144 + fn * 16 + lm;
        float bv = -INFINITY;
        if (c < C_) {
            float px = prow[c * 2], py = prow[c * 2 + 1];
            bv = (px == -0.1f && py == -0.1f) ? -INFINITY : 0.0f;
        }
        bias[fn] = bv;
    }

    f32x4 acc[3][9];
    #pragma unroll
    for (int i = 0; i < 3; ++i)
        #pragma unroll
        for (int j = 0; j < 9; ++j) { f32x4 z = {0.f, 0.f, 0.f, 0.f}; acc[i][j] = z; }

    auto compute = [&](int cb) {
        const ushort* As = (const ushort*)(LdsU + cb * 6144);
        const ushort* Bs = (const ushort*)(LdsU + cb * 6144 + 1536);
        short8 av[3];
        #pragma unroll
        for (int fm = 0; fm < 3; ++fm)
            av[fm] = *(const short8*)(As + (wm * 48 + fm * 16 + lm) * 32 + lq * 8);
        #pragma unroll
        for (int fn = 0; fn < 9; ++fn) {
            short8 bv = *(const short8*)(Bs + (wn * 144 + fn * 16 + lm) * 32 + lq * 8);
            #pragma unroll
            for (int fm = 0; fm < 3; ++fm)
                acc[fm][fn] = __builtin_amdgcn_mfma_f32_16x16x32_bf16(av[fm], bv, acc[fm][fn], 0, 0, 0);
        }
    };

    int cur = 0;
    stage2<6, 18, 1536>(Ab, Bb, LdsU, wid, lane);
    __syncthreads();
    for (int k = 0; k < 8; ++k) {
        int nk = (k + 1) * 32;
        stage2<6, 18, 1536>(Ab + nk, Bb + nk, LdsU + (cur ^ 1) * 6144, wid, lane);
        compute(cur);
        __syncthreads();
        cur ^= 1;
    }
    compute(cur);

    // ---- softmax over c per row (row = o0+wm*48+fm*16+lq*4+r) ----
    float mx[3][4];
    #pragma unroll
    for (int fm = 0; fm < 3; ++fm)
        #pragma unroll
        for (int r = 0; r < 4; ++r) {
            float m = -INFINITY;
            #pragma unroll
            for (int fn = 0; fn < 9; ++fn) m = fmaxf(m, acc[fm][fn][r] + bias[fn]);
            #pragma unroll
            for (int off = 1; off < 16; off <<= 1) m = fmaxf(m, __shfl_xor(m, off, 64));
            mx[fm][r] = m;
        }
    if (lm == 0) {
        #pragma unroll
        for (int fm = 0; fm < 3; ++fm)
            #pragma unroll
            for (int r = 0; r < 4; ++r)
                red[0][wn][wm * 48 + fm * 16 + lq * 4 + r] = mx[fm][r];
    }
    __syncthreads();
    float Mv[3][4], sm[3][4];
    #pragma unroll
    for (int fm = 0; fm < 3; ++fm)
        #pragma unroll
        for (int r = 0; r < 4; ++r) {
            int row = wm * 48 + fm * 16 + lq * 4 + r;
            Mv[fm][r] = fmaxf(red[0][0][row], red[0][1][row]);
            sm[fm][r] = 0.f;
        }
    #pragma unroll
    for (int fm = 0; fm < 3; ++fm)
        #pragma unroll
        for (int fn = 0; fn < 9; ++fn)
            #pragma unroll
            for (int r = 0; r < 4; ++r) {
                float e = __expf(acc[fm][fn][r] + bias[fn] - Mv[fm][r]);
                acc[fm][fn][r] = e;
                sm[fm][r] += e;
            }
    #pragma unroll
    for (int fm = 0; fm < 3; ++fm)
        #pragma unroll
        for (int r = 0; r < 4; ++r) {
            #pragma unroll
            for (int off = 1; off < 16; off <<= 1) sm[fm][r] += __shfl_xor(sm[fm][r], off, 64);
        }
    if (lm == 0) {
        #pragma unroll
        for (int fm = 0; fm < 3; ++fm)
            #pragma unroll
            for (int r = 0; r < 4; ++r)
                red[1][wn][wm * 48 + fm * 16 + lq * 4 + r] = sm[fm][r];
    }
    __syncthreads();
    ushort* Wb = wbf + (size_t)b * OP_ * KP_;
    #pragma unroll
    for (int fm = 0; fm < 3; ++fm)
        #pragma unroll
        for (int r = 0; r < 4; ++r) {
            int row = wm * 48 + fm * 16 + lq * 4 + r;
            float inv = 1.0f / (red[1][0][row] + red[1][1][row]);
            ushort* wr = Wb + (size_t)(o0 + row) * KP_ + wn * 144 + lm;
            #pragma unroll
            for (int fn = 0; fn < 9; ++fn)
                wr[fn * 16] = f2bf(acc[fm][fn][r] * inv);
        }
}

// ---------------------------------------------------------------------------
// K4: megT = bf16 transpose of meg for a chunk of b: [nb][T_][KP_], c>=273 zero.
// ---------------------------------------------------------------------------
__global__ __launch_bounds__(256) void k_megT(const float* __restrict__ meg,
                                              ushort* __restrict__ megT, int b0) {
    __shared__ float lds[64 * 65];
    int bl = blockIdx.z;
    int t0 = blockIdx.x * 64;
    int c0 = blockIdx.y * 64;
    int tid = threadIdx.x;
    const float* Mb = meg + (size_t)(b0 + bl) * C_ * T_;
    #pragma unroll
    for (int i = 0; i < 4; ++i) {
        int slot = tid + i * 256;
        int r = slot >> 4, q = slot & 15;
        float4 v = make_float4(0.f, 0.f, 0.f, 0.f);
        if (c0 + r < C_) v = *(const float4*)(Mb + (size_t)(c0 + r) * T_ + t0 + q * 4);
        lds[r * 65 + q * 4 + 0] = v.x;
        lds[r * 65 + q * 4 + 1] = v.y;
        lds[r * 65 + q * 4 + 2] = v.z;
        lds[r * 65 + q * 4 + 3] = v.w;
    }
    __syncthreads();
    ushort* Tb = megT + (size_t)bl * T_ * KP_;
    #pragma unroll
    for (int i = 0; i < 2; ++i) {
        int slot = tid + i * 256;
        int t = slot >> 3, co = (slot & 7) * 8;
        int c = c0 + co;
        if (c >= KP_) continue;
        uint4 w;
        w.x = pack2bf(lds[(co + 0) * 65 + t], lds[(co + 1) * 65 + t]);
        w.y = pack2bf(lds[(co + 2) * 65 + t], lds[(co + 3) * 65 + t]);
        w.z = pack2bf(lds[(co + 4) * 65 + t], lds[(co + 5) * 65 + t]);
        w.w = pack2bf(lds[(co + 6) * 65 + t], lds[(co + 7) * 65 + t]);
        *(uint4*)(Tb + (size_t)(t0 + t) * KP_ + c) = w;
    }
}

// ---------------------------------------------------------------------------
// K5: out = wbf @ megT. M=288 (full O), N=128 t, K=288. Waves 2x2, wave-tile
// 144x64 = 9fm x 4fn -> 36 MFMA per wave-step (3x old density). 2-phase dbuf
// glds; bijective XCD swizzle keeps a b's 16 t-blocks on one XCD (A reuse).
// ---------------------------------------------------------------------------
__global__ __launch_bounds__(256) void k_out(const ushort* __restrict__ megT,
                                             const ushort* __restrict__ wbf,
                                             float* __restrict__ out,
                                             int b0, int nb) {
    __shared__ uint LdsU[2 * 6656];      // per buf: A 288x32 (4608u) + B 128x32 (2048u)
    int d  = xcd_swz(blockIdx.x, 16 * nb);
    int tb = d & 15, bl = d >> 4;
    int b  = b0 + bl;
    int t0 = tb * 128;
    int tid = threadIdx.x;
    int wid = tid >> 6, lane = tid & 63;
    int wm = wid >> 1, wn = wid & 1;
    int lm = lane & 15, lq = lane >> 4;
    const ushort* Ab = wbf  + (size_t)b * OP_ * KP_;
    const ushort* Bb = megT + ((size_t)bl * T_ + t0) * KP_;
    f32x4 acc[9][4];
    #pragma unroll
    for (int i = 0; i < 9; ++i)
        #pragma unroll
        for (int j = 0; j < 4; ++j) { f32x4 z = {0.f, 0.f, 0.f, 0.f}; acc[i][j] = z; }

    auto compute = [&](int cb) {
        const ushort* As = (const ushort*)(LdsU + cb * 6656);
        const ushort* Bs = (const ushort*)(LdsU + cb * 6656 + 4608);
        short8 bv[4];
        #pragma unroll
        for (int fn = 0; fn < 4; ++fn)
            bv[fn] = *(const short8*)(Bs + (wn * 64 + fn * 16 + lm) * 32 + lq * 8);
        #pragma unroll
        for (int fm = 0; fm < 9; ++fm) {
            short8 av = *(const short8*)(As + (wm * 144 + fm * 16 + lm) * 32 + lq * 8);
            #pragma unroll
            for (int fn = 0; fn < 4; ++fn)
                acc[fm][fn] = __builtin_amdgcn_mfma_f32_16x16x32_bf16(av, bv[fn], acc[fm][fn], 0, 0, 0);
        }
    };

    int cur = 0;
    stage2<18, 8, 4608>(Ab, Bb, LdsU, wid, lane);
    __syncthreads();
    for (int k = 0; k < 8; ++k) {
        int nk = (k + 1) * 32;
        stage2<18, 8, 4608>(Ab + nk, Bb + nk, LdsU + (cur ^ 1) * 6656, wid, lane);
        compute(cur);
        __syncthreads();
        cur ^= 1;
    }
    compute(cur);

    #pragma unroll
    for (int fm = 0; fm < 9; ++fm) {
        int obase = wm * 144 + fm * 16 + lq * 4;
        #pragma unroll
        for (int fn = 0; fn < 4; ++fn) {
            int t = t0 + wn * 64 + fn * 16 + lm;
            #pragma unroll
            for (int r = 0; r < 4; ++r) {
                int o = obase + r;
                if (o < O_) out[((size_t)b * O_ + o) * T_ + t] = acc[fm][fn][r];
            }
        }
    }
}

// ---------------------------------------------------------------------------
extern "C" void kernel_launch(void* const* d_in, const int* in_sizes, int n_in,
                              void* d_out, int out_size, void* d_ws, size_t ws_size,
                              hipStream_t stream) {
    const float* meg   = (const float*)d_in[0];
    const float* pos   = (const float*)d_in[1];
    const int*   sids  = (const int*)d_in[2];
    const float* heads = (const float*)d_in[3];
    float* out = (float*)d_out;

    // ws layout: [emb 21.2MB | hb 21.2MB | wbf 21.2MB | megT chunk(s)]
    // megT chunk size adapts to ws_size (1.18 MB per b); ws>=65MB works.
    const size_t embE = (size_t)B_ * CP_ * D_;   // ushorts (=hb/wbf size)
    ushort* emb  = (ushort*)d_ws;
    ushort* hb   = emb + embE;
    ushort* wbf  = hb + embE;
    ushort* megT = wbf + embE;
    const size_t perB = (size_t)T_ * KP_ * 2;    // bytes per b of megT
    size_t avail = ws_size > 3 * embE * 2 ? ws_size - 3 * embE * 2 : 0;
    int chunkB = (int)(avail / perB);
    if (chunkB > B_) chunkB = B_;
    if (chunkB < 1) chunkB = 1;  // ws contract: >= ~66MB

    k_emb<<<(B_ * CP_ * 144 + 255) / 256, 256, 0, stream>>>(pos, emb);
    k_gather<<<(B_ * OP_ * 36 + 255) / 256, 256, 0, stream>>>(heads, sids, hb);
    k_fused<<<3 * B_, 256, 0, stream>>>(hb, emb, pos, wbf);
    for (int b0 = 0; b0 < B_; b0 += chunkB) {
        int nb = (B_ - b0 < chunkB) ? (B_ - b0) : chunkB;
        k_megT<<<dim3(T_ / 64, 5, nb), 256, 0, stream>>>(meg, megT, b0);
        k_out<<<16 * nb, 256, 0, stream>>>(megT, wbf, out, b0, nb);
    }
}